// Round 7
// baseline (562.243 us; speedup 1.0000x reference)
//
#include <hip/hip_runtime.h>
#include <hip/hip_bf16.h>

// Problem constants
#define BSZ      2
#define LTOK     21760            // 128*128 + 64*64 + 32*32 + 16*16
#define NTOK     (BSZ * LTOK)     // 43520 = 128 * 340
#define DMODEL   256
#define DFFN     1024

typedef __attribute__((ext_vector_type(8))) short short8;   // 8 bf16 = 4 VGPRs
typedef __attribute__((ext_vector_type(4))) float f32x4;

__device__ __forceinline__ unsigned short f2bf(float x) {
    __hip_bfloat16 h = __float2bfloat16(x);
    return *reinterpret_cast<unsigned short*>(&h);
}
__device__ __forceinline__ float bf2f(unsigned short u) {
    union { unsigned int i; float f; } c; c.i = ((unsigned int)u) << 16; return c.f;
}
__device__ __forceinline__ float bflo(unsigned int u) {
    union { unsigned int i; float f; } c; c.i = u << 16; return c.f;
}
__device__ __forceinline__ float bfhi(unsigned int u) {
    union { unsigned int i; float f; } c; c.i = u & 0xffff0000u; return c.f;
}

// ---------------------------------------------------------------------------
// bf16 MFMA GEMM:  C[M x N] = A @ Bt^T + bias, A bf16 [M][K], Bt bf16 [N][K].
// Tile 128(M) x 256(N), BK=32. 4 waves 2x2 (wm: 64 rows, wn: 128 cols),
// each wave 4x8 MFMA tiles of 16x16x32 -> 32 MFMA per K-step.
// LDS fragment order: sub-tile (16 rows x 32 k) = 64 slots x 16 B at lane*16.
// N-guard: B row clamp + store guard (qproj N=384 uses grid.x=2).
// Epilogue: LDS-staged slabs (32 rows x 256 cols), uint4 full-line stores.
// cmode 0: row-major.  cmode 1: head-major vT[((b*8+h)*LTOK+s)*32+d] (N=256).
// ---------------------------------------------------------------------------
#define TM 128
#define TN 256
#define TBK 32
#define EBS 264   // epilogue LDS row stride in ushorts (x2B = 528 B, 16B-aligned)

__global__ __launch_bounds__(256, 2) void gemm_mfma(
    const unsigned short* __restrict__ A,
    const unsigned short* __restrict__ Bt, const float* __restrict__ bias,
    unsigned short* __restrict__ Cb,
    int M, int N, int K, int relu, int cmode,
    const unsigned char* __restrict__ mask)
{
    // A: 128*32 = 4096 ushorts (8 KB); B: 256*32 = 8192 ushorts (16 KB)
    __shared__ __align__(16) unsigned short smem[TM * TBK + TN * TBK];
    unsigned short* sA = smem;
    unsigned short* sB = smem + TM * TBK;

    const int tid  = threadIdx.x;
    const int lane = tid & 63;
    const int wave = tid >> 6;
    const int wm = wave >> 1, wn = wave & 1;

    const int bm = blockIdx.y * TM;
    const int bn = blockIdx.x * TN;

    const int sr = tid >> 6;           // staging sub-tile base (0..3)
    const int fr = lane & 15;          // row within sub-tile
    const int fk = (lane >> 4) * 8;    // k offset (0,8,16,24)

    f32x4 acc[4][8];
    #pragma unroll
    for (int i = 0; i < 4; ++i)
        #pragma unroll
        for (int j = 0; j < 8; ++j)
            acc[i][j] = (f32x4){0.f, 0.f, 0.f, 0.f};

    for (int k0 = 0; k0 < K; k0 += TBK) {
        // stage A: 8 sub-tiles, 2 per thread-group
        #pragma unroll
        for (int rr = 0; rr < 2; ++rr) {
            const int s = sr + rr * 4;
            const size_t grow = (size_t)(bm + s * 16 + fr);
            *(uint4*)&sA[s * 512 + lane * 8] = *(const uint4*)(A + grow * K + k0 + fk);
        }
        // stage B: 16 sub-tiles, 4 per thread-group (row clamp for N-guard)
        #pragma unroll
        for (int rr = 0; rr < 4; ++rr) {
            const int s = sr + rr * 4;
            int gn = bn + s * 16 + fr;
            gn = min(gn, N - 1);
            *(uint4*)&sB[s * 512 + lane * 8] = *(const uint4*)(Bt + (size_t)gn * K + k0 + fk);
        }
        __syncthreads();

        short8 af[4], bfr[8];
        #pragma unroll
        for (int i = 0; i < 4; ++i)
            af[i] = *(const short8*)&sA[(wm * 4 + i) * 512 + lane * 8];
        #pragma unroll
        for (int j = 0; j < 8; ++j)
            bfr[j] = *(const short8*)&sB[(wn * 8 + j) * 512 + lane * 8];
        #pragma unroll
        for (int i = 0; i < 4; ++i)
            #pragma unroll
            for (int j = 0; j < 8; ++j)
                acc[i][j] = __builtin_amdgcn_mfma_f32_16x16x32_bf16(
                    af[i], bfr[j], acc[i][j], 0, 0, 0);
        __syncthreads();
    }

    // ---- vectorized epilogue: slabs of 32 rows x 256 cols ----
    // MFMA C/D layout: col = lane&15, row = (lane>>4)*4 + reg.
    const int r0 = (lane >> 4) * 4;
    const int c0 = lane & 15;
    unsigned short* eb = smem;   // 32*EBS = 8448 ushorts <= 12288 available

    #pragma unroll
    for (int i = 0; i < 4; ++i) {
        if (i) __syncthreads();          // previous slab's reads done
        #pragma unroll
        for (int j = 0; j < 8; ++j) {
            const int col = bn + wn * 128 + j * 16 + c0;
            const float bj = (col < N) ? bias[col] : 0.f;
            #pragma unroll
            for (int r = 0; r < 4; ++r) {
                const int row = bm + wm * 64 + i * 16 + r0 + r;
                float v = acc[i][j][r] + bj;
                if (relu) v = fmaxf(v, 0.f);
                if (mask && mask[row]) v = 0.f;
                eb[(wm * 16 + r0 + r) * EBS + wn * 128 + j * 16 + c0] = f2bf(v);
            }
        }
        __syncthreads();                 // slab staged
        #pragma unroll
        for (int qq = 0; qq < 4; ++qq) {
            const int q  = tid + qq * 256;        // 1024 chunks = 32 rows x 32
            const int rl = q >> 5;                // stage row 0..31 (wm*16 + rr)
            const int ch = q & 31;                // 16 B chunk within 256 cols
            const int grow = bm + (rl >> 4) * 64 + i * 16 + (rl & 15);
            const int colb = bn + ch * 8;
            if (colb < N) {
                const uint4 val = *(const uint4*)&eb[rl * EBS + ch * 8];
                if (cmode == 1) {
                    const int bb   = grow >= LTOK;
                    const int srow = grow - bb * LTOK;
                    const int hcol = ch >> 2;             // head (N==256, bn==0)
                    const int d    = (ch & 3) * 8;
                    *(uint4*)&Cb[((size_t)(bb * 8 + hcol) * LTOK + srow) * 32 + d] = val;
                } else {
                    *(uint4*)&Cb[(size_t)grow * N + colb] = val;
                }
            }
        }
    }
}

// ---------------------------------------------------------------------------
// Prepass: sb = bf16(src), qs = bf16(src + pos). Vectorized x4.
// ---------------------------------------------------------------------------
__global__ __launch_bounds__(256) void prepass(
    const float* __restrict__ src, const float* __restrict__ pos,
    unsigned short* __restrict__ sb, unsigned short* __restrict__ qs)
{
    const size_t i = ((size_t)blockIdx.x * 256 + threadIdx.x) * 4;
    const float4 s = *(const float4*)(src + i);
    const float4 p = *(const float4*)(pos + i);
    ushort4 us, uq;
    us.x = f2bf(s.x); us.y = f2bf(s.y); us.z = f2bf(s.z); us.w = f2bf(s.w);
    uq.x = f2bf(s.x + p.x); uq.y = f2bf(s.y + p.y);
    uq.z = f2bf(s.z + p.z); uq.w = f2bf(s.w + p.w);
    *(ushort4*)(sb + i) = us;
    *(ushort4*)(qs + i) = uq;
}

// ---------------------------------------------------------------------------
// All weight transposes (f32 [K][N] -> bf16 [N][K]) + bias concat, 1 dispatch.
// 32x32 tiles; block ranges hardcoded for the fixed problem shapes.
// ---------------------------------------------------------------------------
__global__ void transpose_all(
    const float* __restrict__ w_val, const float* __restrict__ w_off,
    const float* __restrict__ w_att, const float* __restrict__ w_out,
    const float* __restrict__ w1,    const float* __restrict__ w2,
    const float* __restrict__ b_off, const float* __restrict__ b_att,
    unsigned short* __restrict__ wvalT, unsigned short* __restrict__ woaT,
    unsigned short* __restrict__ woutT, unsigned short* __restrict__ w1T,
    unsigned short* __restrict__ w2T,   float* __restrict__ bcat)
{
    const int blk = blockIdx.x;
    const int tx = threadIdx.x, ty = threadIdx.y;   // 32 x 8
    if (blk == 736) {
        const int t = ty * 32 + tx;
        bcat[t] = (t < 256) ? b_off[t] : b_att[t - 256];
        if (t + 256 < 384) bcat[t + 256] = b_att[t + 256 - 256];
        return;
    }
    const float* W; unsigned short* Wt; int K, N, base;
    if      (blk < 64)  { W = w_val; Wt = wvalT;           K = 256;  N = 256;  base = 0;   }
    else if (blk < 128) { W = w_off; Wt = woaT;            K = 256;  N = 256;  base = 64;  }
    else if (blk < 160) { W = w_att; Wt = woaT + 256*256;  K = 256;  N = 128;  base = 128; }
    else if (blk < 224) { W = w_out; Wt = woutT;           K = 256;  N = 256;  base = 160; }
    else if (blk < 480) { W = w1;    Wt = w1T;             K = 256;  N = 1024; base = 224; }
    else                { W = w2;    Wt = w2T;             K = 1024; N = 256;  base = 480; }
    const int local = blk - base;
    const int kb = local % (K / 32);
    const int nb = local / (K / 32);
    const int k0 = kb * 32, n0 = nb * 32;

    __shared__ float t[32][33];
    #pragma unroll
    for (int i = 0; i < 32; i += 8)
        t[ty + i][tx] = W[(size_t)(k0 + ty + i) * N + n0 + tx];
    __syncthreads();
    #pragma unroll
    for (int i = 0; i < 32; i += 8)
        Wt[(size_t)(n0 + ty + i) * K + k0 + tx] = f2bf(t[tx][ty + i]);
}

// ---------------------------------------------------------------------------
// Fused softmax + bilinear sampling, head-major value, qp bf16.
// Block = (plane, 16-token chunk); plane = blockIdx % 16 pins a plane to one
// XCD. SoA LDS (s_w[c][256], s_o[c][256]): phase-B tl-stride = 64 B = 16
// banks -> 2-way (free) instead of round 6's 4-way 256 B-stride conflict.
// ---------------------------------------------------------------------------
__global__ __launch_bounds__(256) void sample_kernel(
    const unsigned short* __restrict__ vT, const unsigned short* __restrict__ qp,
    const float* __restrict__ ref,
    const int* __restrict__ sshapes, const int* __restrict__ lstart,
    unsigned short* __restrict__ samp)
{
    __shared__ float s_w[4][256];
    __shared__ int   s_o[4][256];   // byte offsets into the plane

    const int blk   = blockIdx.x;
    const int plane = blk & 15;
    const int chunk = blk >> 4;              // 0 .. LTOK/16-1
    const int b = plane >> 3;
    const int h = plane & 7;
    const int s0 = chunk * 16;               // token offset within plane
    const int t = threadIdx.x;

    // ---- phase A: per (token, point) ----
    {
        const int tl = t >> 4;               // 0..15 token in chunk
        const int p  = t & 15;
        const int l  = p >> 2;
        const int pp = p & 3;
        const int H = sshapes[2 * l], W = sshapes[2 * l + 1];
        const float Wf = (float)W, Hf = (float)H;
        const size_t tok = (size_t)(b * LTOK + s0 + tl);

        const float ox = bf2f(qp[tok * 384 + h * 32 + l * 8 + pp * 2 + 0]);
        const float oy = bf2f(qp[tok * 384 + h * 32 + l * 8 + pp * 2 + 1]);
        const float rx = ref[tok * 8 + l * 2 + 0];
        const float ry = ref[tok * 8 + l * 2 + 1];

        const float x = (rx + ox / Wf) * Wf - 0.5f;
        const float y = (ry + oy / Hf) * Hf - 0.5f;
        const float x0 = floorf(x), y0 = floorf(y);
        const float dx = x - x0, dy = y - y0;
        const int x0i = (int)x0, y0i = (int)y0;
        const int s = lstart[l];

        // softmax over the 16 points of this head (16-lane groups)
        const float a = bf2f(qp[tok * 384 + 256 + h * 16 + p]);
        float mx = a;
        #pragma unroll
        for (int m = 8; m; m >>= 1) mx = fmaxf(mx, __shfl_xor(mx, m, 16));
        const float e = __expf(a - mx);
        float ssum = e;
        #pragma unroll
        for (int m = 8; m; m >>= 1) ssum += __shfl_xor(ssum, m, 16);
        const float prob = e / ssum;

        const float cw[4] = {(1.f - dx) * (1.f - dy), dx * (1.f - dy),
                             (1.f - dx) * dy,         dx * dy};
        const int cx[4] = {x0i, x0i + 1, x0i,     x0i + 1};
        const int cy[4] = {y0i, y0i,     y0i + 1, y0i + 1};
        #pragma unroll
        for (int c = 0; c < 4; ++c) {
            const bool valid = (cx[c] >= 0) & (cx[c] < W) & (cy[c] >= 0) & (cy[c] < H);
            const int xi = min(max(cx[c], 0), W - 1);
            const int yi = min(max(cy[c], 0), H - 1);
            s_o[c][t] = (s + yi * W + xi) * 64;          // byte offset (32 bf16)
            s_w[c][t] = valid ? cw[c] * prob : 0.f;
        }
    }
    __syncthreads();

    // ---- phase B: gather-accumulate, (token, dim-pair) ----
    const int tl = t >> 4;                   // 0..15
    const int dp = t & 15;                   // dim pair 0..15
    const char* vp = (const char*)(vT + (size_t)plane * LTOK * 32) + dp * 4;
    float acc0 = 0.f, acc1 = 0.f;
    #pragma unroll
    for (int p = 0; p < 16; ++p) {
        const int sl = tl * 16 + p;
        #pragma unroll
        for (int c = 0; c < 4; ++c) {
            const float w = s_w[c][sl];
            const unsigned int u = *(const unsigned int*)(vp + s_o[c][sl]);
            acc0 = fmaf(w, bflo(u), acc0);
            acc1 = fmaf(w, bfhi(u), acc1);
        }
    }
    const unsigned int o = (unsigned)f2bf(acc0) | ((unsigned)f2bf(acc1) << 16);
    *(unsigned int*)(samp + (size_t)(b * LTOK + s0 + tl) * 256 + h * 32 + dp * 2) = o;
}

// ---------------------------------------------------------------------------
// LayerNorm over D=256: out = LN(a + b) * g + be; a,b bf16. One wave/token.
// ---------------------------------------------------------------------------
__global__ __launch_bounds__(256) void ln_kernel(
    const unsigned short* __restrict__ a, const unsigned short* __restrict__ b,
    const float* __restrict__ g, const float* __restrict__ be,
    float* __restrict__ outF, unsigned short* __restrict__ outB)
{
    const int wid  = threadIdx.x >> 6;
    const int lane = threadIdx.x & 63;
    const int tok  = blockIdx.x * 4 + wid;
    const size_t base = (size_t)tok * 256 + lane * 4;

    const ushort4 ua = *(const ushort4*)(a + base);
    const ushort4 ub = *(const ushort4*)(b + base);
    float4 v;
    v.x = bf2f(ua.x) + bf2f(ub.x);
    v.y = bf2f(ua.y) + bf2f(ub.y);
    v.z = bf2f(ua.z) + bf2f(ub.z);
    v.w = bf2f(ua.w) + bf2f(ub.w);

    float s  = v.x + v.y + v.z + v.w;
    float sq = v.x * v.x + v.y * v.y + v.z * v.z + v.w * v.w;
    #pragma unroll
    for (int m = 32; m; m >>= 1) {
        s  += __shfl_xor(s, m, 64);
        sq += __shfl_xor(sq, m, 64);
    }
    const float mean = s * (1.f / 256.f);
    const float var  = sq * (1.f / 256.f) - mean * mean;
    const float rs   = rsqrtf(var + 1e-5f);

    const float4 g4 = *(const float4*)(g + lane * 4);
    const float4 b4 = *(const float4*)(be + lane * 4);
    float4 o;
    o.x = (v.x - mean) * rs * g4.x + b4.x;
    o.y = (v.y - mean) * rs * g4.y + b4.y;
    o.z = (v.z - mean) * rs * g4.z + b4.z;
    o.w = (v.w - mean) * rs * g4.w + b4.w;
    if (outF) *(float4*)(outF + base) = o;
    if (outB) {
        ushort4 u;
        u.x = f2bf(o.x); u.y = f2bf(o.y); u.z = f2bf(o.z); u.w = f2bf(o.w);
        *(ushort4*)(outB + base) = u;
    }
}

// ---------------------------------------------------------------------------
extern "C" void kernel_launch(void* const* d_in, const int* in_sizes, int n_in,
                              void* d_out, int out_size, void* d_ws, size_t ws_size,
                              hipStream_t stream)
{
    const float* src   = (const float*)d_in[0];
    const float* pos   = (const float*)d_in[1];
    const float* ref   = (const float*)d_in[2];
    const int*   sshap = (const int*)d_in[3];
    const int*   lstrt = (const int*)d_in[4];
    const unsigned char* mask = (const unsigned char*)d_in[5];
    const float* w_off = (const float*)d_in[6];
    const float* b_off = (const float*)d_in[7];
    const float* w_att = (const float*)d_in[8];
    const float* b_att = (const float*)d_in[9];
    const float* w_val = (const float*)d_in[10];
    const float* b_val = (const float*)d_in[11];
    const float* w_out = (const float*)d_in[12];
    const float* b_out = (const float*)d_in[13];
    const float* ln1g  = (const float*)d_in[14];
    const float* ln1b  = (const float*)d_in[15];
    const float* w1    = (const float*)d_in[16];
    const float* b1    = (const float*)d_in[17];
    const float* w2    = (const float*)d_in[18];
    const float* b2    = (const float*)d_in[19];
    const float* ln2g  = (const float*)d_in[20];
    const float* ln2b  = (const float*)d_in[21];
    float* out = (float*)d_out;

    // ---- workspace (~146 MB), time-disjoint reuse ----
    // HSZ = NTOK*256*2 = 22.28 MB
    // [0,      HSZ)          qs    -> samp16 (qs dead after qproj)
    // [HSZ,    HSZ+1.5HSZ)   qpb [NTOK][384] bf16
    // [2.5HSZ, 3.5HSZ)       vT head-major bf16
    // [3.5HSZ, 4.5HSZ)       aof16 bf16
    // [0,      4HSZ)         hidb [NTOK][1024] bf16 (after LN1: overlaps
    //                        samp/qpb/vT/aof16, all dead)
    // [4.5HSZ, 5.5HSZ)       sb bf16 -> ffb bf16 (sb dead after LN1)
    // [5.5HSZ, 6.5HSZ)       xb bf16
    // [6.5HSZ, +1.5 MB)      weights bf16 + bias concat
    const size_t HSZ = (size_t)NTOK * 256 * 2;
    char* w = (char*)d_ws;
    unsigned short* qs     = (unsigned short*)w;
    unsigned short* samp16 = (unsigned short*)w;
    unsigned short* qpb    = (unsigned short*)(w + HSZ);
    unsigned short* vT     = (unsigned short*)(w + HSZ * 5 / 2);
    unsigned short* aof16  = (unsigned short*)(w + HSZ * 7 / 2);
    unsigned short* hidb   = (unsigned short*)w;
    unsigned short* sb     = (unsigned short*)(w + HSZ * 9 / 2);
    unsigned short* ffb    = sb;
    unsigned short* xb     = (unsigned short*)(w + HSZ * 11 / 2);
    char* wreg = w + HSZ * 13 / 2;
    unsigned short* wvalT  = (unsigned short*)wreg;
    unsigned short* woaT   = wvalT + 256 * 256;       // [384][256]
    unsigned short* woutT  = woaT + 384 * 256;
    unsigned short* w1T    = woutT + 256 * 256;
    unsigned short* w2T    = w1T + 1024 * 256;
    float*          bcat   = (float*)(w2T + 256 * 1024);

    const dim3 blk(256);

    // 1. prepass: sb = bf16(src), qs = bf16(src+pos)
    prepass<<<dim3(NTOK / 4), blk, 0, stream>>>(src, pos, sb, qs);

    // 2. all weight transposes + bias concat (one dispatch)
    transpose_all<<<dim3(737), dim3(32, 8), 0, stream>>>(
        w_val, w_off, w_att, w_out, w1, w2, b_off, b_att,
        wvalT, woaT, woutT, w1T, w2T, bcat);

    // 3. value = sb @ w_val + b_val (masked) -> vT head-major
    gemm_mfma<<<dim3(1, NTOK / TM), blk, 0, stream>>>(
        sb, wvalT, b_val, vT, NTOK, 256, 256, 0, 1, mask);

    // 4. qproj = qs @ [w_off|w_att] + bcat -> qpb [NTOK][384]
    gemm_mfma<<<dim3(2, NTOK / TM), blk, 0, stream>>>(
        qs, woaT, bcat, qpb, NTOK, 384, 256, 0, 0, nullptr);

    // 5. softmax + bilinear sampling -> samp16 (qs dead)
    sample_kernel<<<dim3(16 * (LTOK / 16)), blk, 0, stream>>>(
        vT, qpb, ref, sshap, lstrt, samp16);

    // 6. attn_out = samp @ w_out + b_out -> aof16
    gemm_mfma<<<dim3(1, NTOK / TM), blk, 0, stream>>>(
        samp16, woutT, b_out, aof16, NTOK, 256, 256, 0, 0, nullptr);

    // 7. x = LN1(sb + aof16) -> xb bf16
    ln_kernel<<<dim3(NTOK / 4), blk, 0, stream>>>(
        sb, aof16, ln1g, ln1b, nullptr, xb);

    // 8. hidden = relu(xb @ w1 + b1) -> hidb (overlays dead regions)
    gemm_mfma<<<dim3(4, NTOK / TM), blk, 0, stream>>>(
        xb, w1T, b1, hidb, NTOK, DFFN, 256, 1, 0, nullptr);

    // 9. ffn = hidb @ w2 + b2 -> ffb (sb region, dead)
    gemm_mfma<<<dim3(1, NTOK / TM), blk, 0, stream>>>(
        hidb, w2T, b2, ffb, NTOK, 256, DFFN, 0, 0, nullptr);

    // 10. out = LN2(xb + ffb)
    ln_kernel<<<dim3(NTOK / 4), blk, 0, stream>>>(
        xb, ffb, ln2g, ln2b, out, nullptr);
}

// Round 8
// 482.174 us; speedup vs baseline: 1.1661x; 1.1661x over previous
//
#include <hip/hip_runtime.h>
#include <hip/hip_bf16.h>

// Problem constants
#define BSZ      2
#define LTOK     21760            // 128*128 + 64*64 + 32*32 + 16*16
#define NTOK     (BSZ * LTOK)     // 43520 = 128 * 340
#define DMODEL   256
#define DFFN     1024

typedef __attribute__((ext_vector_type(8))) short short8;   // 8 bf16 = 4 VGPRs
typedef __attribute__((ext_vector_type(4))) float f32x4;

__device__ __forceinline__ unsigned short f2bf(float x) {
    __hip_bfloat16 h = __float2bfloat16(x);
    return *reinterpret_cast<unsigned short*>(&h);
}
__device__ __forceinline__ float bf2f(unsigned short u) {
    union { unsigned int i; float f; } c; c.i = ((unsigned int)u) << 16; return c.f;
}
__device__ __forceinline__ float bflo(unsigned int u) {
    union { unsigned int i; float f; } c; c.i = u << 16; return c.f;
}
__device__ __forceinline__ float bfhi(unsigned int u) {
    union { unsigned int i; float f; } c; c.i = u & 0xffff0000u; return c.f;
}

// ---------------------------------------------------------------------------
// bf16 MFMA GEMM:  C[M x N] = A @ Bt^T + bias, A bf16 [M][K], Bt bf16 [N][K].
// Tile 128(M) x 256(N), BK=32. 4 waves 2x2, each wave 4x8 MFMA 16x16x32.
// Epilogue: LDS-staged slabs, uint4 full-line stores.
// cmode 0: row-major.  cmode 1: head-major vT[((b*8+h)*LTOK+s)*32+d] (N=256).
// ---------------------------------------------------------------------------
#define TM 128
#define TN 256
#define TBK 32
#define EBS 264   // epilogue LDS row stride in ushorts (528 B, 16B-aligned)

__global__ __launch_bounds__(256, 2) void gemm_mfma(
    const unsigned short* __restrict__ A,
    const unsigned short* __restrict__ Bt, const float* __restrict__ bias,
    unsigned short* __restrict__ Cb,
    int M, int N, int K, int relu, int cmode,
    const unsigned char* __restrict__ mask)
{
    __shared__ __align__(16) unsigned short smem[TM * TBK + TN * TBK];
    unsigned short* sA = smem;
    unsigned short* sB = smem + TM * TBK;

    const int tid  = threadIdx.x;
    const int lane = tid & 63;
    const int wave = tid >> 6;
    const int wm = wave >> 1, wn = wave & 1;

    const int bm = blockIdx.y * TM;
    const int bn = blockIdx.x * TN;

    const int sr = tid >> 6;           // staging sub-tile base (0..3)
    const int fr = lane & 15;          // row within sub-tile
    const int fk = (lane >> 4) * 8;    // k offset (0,8,16,24)

    f32x4 acc[4][8];
    #pragma unroll
    for (int i = 0; i < 4; ++i)
        #pragma unroll
        for (int j = 0; j < 8; ++j)
            acc[i][j] = (f32x4){0.f, 0.f, 0.f, 0.f};

    for (int k0 = 0; k0 < K; k0 += TBK) {
        #pragma unroll
        for (int rr = 0; rr < 2; ++rr) {
            const int s = sr + rr * 4;
            const size_t grow = (size_t)(bm + s * 16 + fr);
            *(uint4*)&sA[s * 512 + lane * 8] = *(const uint4*)(A + grow * K + k0 + fk);
        }
        #pragma unroll
        for (int rr = 0; rr < 4; ++rr) {
            const int s = sr + rr * 4;
            int gn = bn + s * 16 + fr;
            gn = min(gn, N - 1);
            *(uint4*)&sB[s * 512 + lane * 8] = *(const uint4*)(Bt + (size_t)gn * K + k0 + fk);
        }
        __syncthreads();

        short8 af[4], bfr[8];
        #pragma unroll
        for (int i = 0; i < 4; ++i)
            af[i] = *(const short8*)&sA[(wm * 4 + i) * 512 + lane * 8];
        #pragma unroll
        for (int j = 0; j < 8; ++j)
            bfr[j] = *(const short8*)&sB[(wn * 8 + j) * 512 + lane * 8];
        #pragma unroll
        for (int i = 0; i < 4; ++i)
            #pragma unroll
            for (int j = 0; j < 8; ++j)
                acc[i][j] = __builtin_amdgcn_mfma_f32_16x16x32_bf16(
                    af[i], bfr[j], acc[i][j], 0, 0, 0);
        __syncthreads();
    }

    // ---- vectorized epilogue: slabs of 32 rows x 256 cols ----
    const int r0 = (lane >> 4) * 4;
    const int c0 = lane & 15;
    unsigned short* eb = smem;

    #pragma unroll
    for (int i = 0; i < 4; ++i) {
        if (i) __syncthreads();
        #pragma unroll
        for (int j = 0; j < 8; ++j) {
            const int col = bn + wn * 128 + j * 16 + c0;
            const float bj = (col < N) ? bias[col] : 0.f;
            #pragma unroll
            for (int r = 0; r < 4; ++r) {
                const int row = bm + wm * 64 + i * 16 + r0 + r;
                float v = acc[i][j][r] + bj;
                if (relu) v = fmaxf(v, 0.f);
                if (mask && mask[row]) v = 0.f;
                eb[(wm * 16 + r0 + r) * EBS + wn * 128 + j * 16 + c0] = f2bf(v);
            }
        }
        __syncthreads();
        #pragma unroll
        for (int qq = 0; qq < 4; ++qq) {
            const int q  = tid + qq * 256;        // 1024 chunks = 32 rows x 32
            const int rl = q >> 5;
            const int ch = q & 31;
            const int grow = bm + (rl >> 4) * 64 + i * 16 + (rl & 15);
            const int colb = bn + ch * 8;
            if (colb < N) {
                const uint4 val = *(const uint4*)&eb[rl * EBS + ch * 8];
                if (cmode == 1) {
                    const int bb   = grow >= LTOK;
                    const int srow = grow - bb * LTOK;
                    const int hcol = ch >> 2;             // head (N==256, bn==0)
                    const int d    = (ch & 3) * 8;
                    *(uint4*)&Cb[((size_t)(bb * 8 + hcol) * LTOK + srow) * 32 + d] = val;
                } else {
                    *(uint4*)&Cb[(size_t)grow * N + colb] = val;
                }
            }
        }
    }
}

// ---------------------------------------------------------------------------
// Prepass: sb = bf16(src), qs = bf16(src + pos). Vectorized x4.
// ---------------------------------------------------------------------------
__global__ __launch_bounds__(256) void prepass(
    const float* __restrict__ src, const float* __restrict__ pos,
    unsigned short* __restrict__ sb, unsigned short* __restrict__ qs)
{
    const size_t i = ((size_t)blockIdx.x * 256 + threadIdx.x) * 4;
    const float4 s = *(const float4*)(src + i);
    const float4 p = *(const float4*)(pos + i);
    ushort4 us, uq;
    us.x = f2bf(s.x); us.y = f2bf(s.y); us.z = f2bf(s.z); us.w = f2bf(s.w);
    uq.x = f2bf(s.x + p.x); uq.y = f2bf(s.y + p.y);
    uq.z = f2bf(s.z + p.z); uq.w = f2bf(s.w + p.w);
    *(ushort4*)(sb + i) = us;
    *(ushort4*)(qs + i) = uq;
}

// ---------------------------------------------------------------------------
// All weight transposes (f32 [K][N] -> bf16 [N][K]) + bias concat, 1 dispatch.
// ---------------------------------------------------------------------------
__global__ void transpose_all(
    const float* __restrict__ w_val, const float* __restrict__ w_off,
    const float* __restrict__ w_att, const float* __restrict__ w_out,
    const float* __restrict__ w1,    const float* __restrict__ w2,
    const float* __restrict__ b_off, const float* __restrict__ b_att,
    unsigned short* __restrict__ wvalT, unsigned short* __restrict__ woaT,
    unsigned short* __restrict__ woutT, unsigned short* __restrict__ w1T,
    unsigned short* __restrict__ w2T,   float* __restrict__ bcat)
{
    const int blk = blockIdx.x;
    const int tx = threadIdx.x, ty = threadIdx.y;   // 32 x 8
    if (blk == 736) {
        const int t = ty * 32 + tx;
        bcat[t] = (t < 256) ? b_off[t] : b_att[t - 256];
        if (t + 256 < 384) bcat[t + 256] = b_att[t];
        return;
    }
    const float* W; unsigned short* Wt; int K, N, base;
    if      (blk < 64)  { W = w_val; Wt = wvalT;           K = 256;  N = 256;  base = 0;   }
    else if (blk < 128) { W = w_off; Wt = woaT;            K = 256;  N = 256;  base = 64;  }
    else if (blk < 160) { W = w_att; Wt = woaT + 256*256;  K = 256;  N = 128;  base = 128; }
    else if (blk < 224) { W = w_out; Wt = woutT;           K = 256;  N = 256;  base = 160; }
    else if (blk < 480) { W = w1;    Wt = w1T;             K = 256;  N = 1024; base = 224; }
    else                { W = w2;    Wt = w2T;             K = 1024; N = 256;  base = 480; }
    const int local = blk - base;
    const int kb = local % (K / 32);
    const int nb = local / (K / 32);
    const int k0 = kb * 32, n0 = nb * 32;

    __shared__ float t[32][33];
    #pragma unroll
    for (int i = 0; i < 32; i += 8)
        t[ty + i][tx] = W[(size_t)(k0 + ty + i) * N + n0 + tx];
    __syncthreads();
    #pragma unroll
    for (int i = 0; i < 32; i += 8)
        Wt[(size_t)(n0 + ty + i) * K + k0 + tx] = f2bf(t[tx][ty + i]);
}

// ---------------------------------------------------------------------------
// Fused softmax + bilinear sampling, head-major value, qp bf16.
// Block = (plane, 16-token chunk); plane = blockIdx % 16 pins a plane to one
// XCD. LDS layout: AoS rows (int4 offsets / float4 weights) indexed p-major:
//   r = p*16 + tl.
// Phase-B read (p fixed, 4 distinct tl per wave): bases 64p + 4*tl words ->
// 4 distinct bank-groups -> conflict-free ds_read_b128 (R6 had 4-way: tl
// stride 256 B; R7's SoA killed the b128s and exposed gather latency).
// ---------------------------------------------------------------------------
__global__ __launch_bounds__(256) void sample_kernel(
    const unsigned short* __restrict__ vT, const unsigned short* __restrict__ qp,
    const float* __restrict__ ref,
    const int* __restrict__ sshapes, const int* __restrict__ lstart,
    unsigned short* __restrict__ samp)
{
    __shared__ __align__(16) int   s_o[256][4];   // byte offsets, row = p*16+tl
    __shared__ __align__(16) float s_w[256][4];   // folded weights, same rows

    const int blk   = blockIdx.x;
    const int plane = blk & 15;
    const int chunk = blk >> 4;              // 0 .. LTOK/16-1
    const int b = plane >> 3;
    const int h = plane & 7;
    const int s0 = chunk * 16;               // token offset within plane
    const int t = threadIdx.x;

    // ---- phase A: per (token, point) ----
    {
        const int tl = t >> 4;               // 0..15 token in chunk
        const int p  = t & 15;
        const int l  = p >> 2;
        const int pp = p & 3;
        const int H = sshapes[2 * l], W = sshapes[2 * l + 1];
        const float Wf = (float)W, Hf = (float)H;
        const size_t tok = (size_t)(b * LTOK + s0 + tl);

        const float ox = bf2f(qp[tok * 384 + h * 32 + l * 8 + pp * 2 + 0]);
        const float oy = bf2f(qp[tok * 384 + h * 32 + l * 8 + pp * 2 + 1]);
        const float rx = ref[tok * 8 + l * 2 + 0];
        const float ry = ref[tok * 8 + l * 2 + 1];

        const float x = (rx + ox / Wf) * Wf - 0.5f;
        const float y = (ry + oy / Hf) * Hf - 0.5f;
        const float x0 = floorf(x), y0 = floorf(y);
        const float dx = x - x0, dy = y - y0;
        const int x0i = (int)x0, y0i = (int)y0;
        const int s = lstart[l];

        // softmax over the 16 points of this head (16-lane groups)
        const float a = bf2f(qp[tok * 384 + 256 + h * 16 + p]);
        float mx = a;
        #pragma unroll
        for (int m = 8; m; m >>= 1) mx = fmaxf(mx, __shfl_xor(mx, m, 16));
        const float e = __expf(a - mx);
        float ssum = e;
        #pragma unroll
        for (int m = 8; m; m >>= 1) ssum += __shfl_xor(ssum, m, 16);
        const float prob = e / ssum;

        const float cw[4] = {(1.f - dx) * (1.f - dy), dx * (1.f - dy),
                             (1.f - dx) * dy,         dx * dy};
        const int cx[4] = {x0i, x0i + 1, x0i,     x0i + 1};
        const int cy[4] = {y0i, y0i,     y0i + 1, y0i + 1};
        int4   o4;
        float4 w4;
        #pragma unroll
        for (int c = 0; c < 4; ++c) {
            const bool valid = (cx[c] >= 0) & (cx[c] < W) & (cy[c] >= 0) & (cy[c] < H);
            const int xi = min(max(cx[c], 0), W - 1);
            const int yi = min(max(cy[c], 0), H - 1);
            ((int*)&o4)[c]   = (s + yi * W + xi) * 64;    // byte offset (32 bf16)
            ((float*)&w4)[c] = valid ? cw[c] * prob : 0.f;
        }
        const int r = p * 16 + tl;           // p-major row index
        *(int4*)&s_o[r][0]   = o4;
        *(float4*)&s_w[r][0] = w4;
    }
    __syncthreads();

    // ---- phase B: gather-accumulate, (token, dim-pair) ----
    const int tl = t >> 4;                   // 0..15
    const int dp = t & 15;                   // dim pair 0..15
    const char* vp = (const char*)(vT + (size_t)plane * LTOK * 32) + dp * 4;
    float acc0 = 0.f, acc1 = 0.f;
    #pragma unroll
    for (int p = 0; p < 16; ++p) {
        const int r = p * 16 + tl;
        const int4   o4 = *(const int4*)&s_o[r][0];
        const float4 w4 = *(const float4*)&s_w[r][0];
        const unsigned int u0 = *(const unsigned int*)(vp + o4.x);
        const unsigned int u1 = *(const unsigned int*)(vp + o4.y);
        const unsigned int u2 = *(const unsigned int*)(vp + o4.z);
        const unsigned int u3 = *(const unsigned int*)(vp + o4.w);
        acc0 = fmaf(w4.x, bflo(u0), acc0); acc1 = fmaf(w4.x, bfhi(u0), acc1);
        acc0 = fmaf(w4.y, bflo(u1), acc0); acc1 = fmaf(w4.y, bfhi(u1), acc1);
        acc0 = fmaf(w4.z, bflo(u2), acc0); acc1 = fmaf(w4.z, bfhi(u2), acc1);
        acc0 = fmaf(w4.w, bflo(u3), acc0); acc1 = fmaf(w4.w, bfhi(u3), acc1);
    }
    const unsigned int o = (unsigned)f2bf(acc0) | ((unsigned)f2bf(acc1) << 16);
    *(unsigned int*)(samp + (size_t)(b * LTOK + s0 + tl) * 256 + h * 32 + dp * 2) = o;
}

// ---------------------------------------------------------------------------
// LayerNorm over D=256: out = LN(a + b) * g + be; a,b bf16. One wave/token.
// ---------------------------------------------------------------------------
__global__ __launch_bounds__(256) void ln_kernel(
    const unsigned short* __restrict__ a, const unsigned short* __restrict__ b,
    const float* __restrict__ g, const float* __restrict__ be,
    float* __restrict__ outF, unsigned short* __restrict__ outB)
{
    const int wid  = threadIdx.x >> 6;
    const int lane = threadIdx.x & 63;
    const int tok  = blockIdx.x * 4 + wid;
    const size_t base = (size_t)tok * 256 + lane * 4;

    const ushort4 ua = *(const ushort4*)(a + base);
    const ushort4 ub = *(const ushort4*)(b + base);
    float4 v;
    v.x = bf2f(ua.x) + bf2f(ub.x);
    v.y = bf2f(ua.y) + bf2f(ub.y);
    v.z = bf2f(ua.z) + bf2f(ub.z);
    v.w = bf2f(ua.w) + bf2f(ub.w);

    float s  = v.x + v.y + v.z + v.w;
    float sq = v.x * v.x + v.y * v.y + v.z * v.z + v.w * v.w;
    #pragma unroll
    for (int m = 32; m; m >>= 1) {
        s  += __shfl_xor(s, m, 64);
        sq += __shfl_xor(sq, m, 64);
    }
    const float mean = s * (1.f / 256.f);
    const float var  = sq * (1.f / 256.f) - mean * mean;
    const float rs   = rsqrtf(var + 1e-5f);

    const float4 g4 = *(const float4*)(g + lane * 4);
    const float4 b4 = *(const float4*)(be + lane * 4);
    float4 o;
    o.x = (v.x - mean) * rs * g4.x + b4.x;
    o.y = (v.y - mean) * rs * g4.y + b4.y;
    o.z = (v.z - mean) * rs * g4.z + b4.z;
    o.w = (v.w - mean) * rs * g4.w + b4.w;
    if (outF) *(float4*)(outF + base) = o;
    if (outB) {
        ushort4 u;
        u.x = f2bf(o.x); u.y = f2bf(o.y); u.z = f2bf(o.z); u.w = f2bf(o.w);
        *(ushort4*)(outB + base) = u;
    }
}

// ---------------------------------------------------------------------------
extern "C" void kernel_launch(void* const* d_in, const int* in_sizes, int n_in,
                              void* d_out, int out_size, void* d_ws, size_t ws_size,
                              hipStream_t stream)
{
    const float* src   = (const float*)d_in[0];
    const float* pos   = (const float*)d_in[1];
    const float* ref   = (const float*)d_in[2];
    const int*   sshap = (const int*)d_in[3];
    const int*   lstrt = (const int*)d_in[4];
    const unsigned char* mask = (const unsigned char*)d_in[5];
    const float* w_off = (const float*)d_in[6];
    const float* b_off = (const float*)d_in[7];
    const float* w_att = (const float*)d_in[8];
    const float* b_att = (const float*)d_in[9];
    const float* w_val = (const float*)d_in[10];
    const float* b_val = (const float*)d_in[11];
    const float* w_out = (const float*)d_in[12];
    const float* b_out = (const float*)d_in[13];
    const float* ln1g  = (const float*)d_in[14];
    const float* ln1b  = (const float*)d_in[15];
    const float* w1    = (const float*)d_in[16];
    const float* b1    = (const float*)d_in[17];
    const float* w2    = (const float*)d_in[18];
    const float* b2    = (const float*)d_in[19];
    const float* ln2g  = (const float*)d_in[20];
    const float* ln2b  = (const float*)d_in[21];
    float* out = (float*)d_out;

    // ---- workspace (~146 MB), time-disjoint reuse ----
    const size_t HSZ = (size_t)NTOK * 256 * 2;    // 22.28 MB
    char* w = (char*)d_ws;
    unsigned short* qs     = (unsigned short*)w;
    unsigned short* samp16 = (unsigned short*)w;
    unsigned short* qpb    = (unsigned short*)(w + HSZ);
    unsigned short* vT     = (unsigned short*)(w + HSZ * 5 / 2);
    unsigned short* aof16  = (unsigned short*)(w + HSZ * 7 / 2);
    unsigned short* hidb   = (unsigned short*)w;
    unsigned short* sb     = (unsigned short*)(w + HSZ * 9 / 2);
    unsigned short* ffb    = sb;
    unsigned short* xb     = (unsigned short*)(w + HSZ * 11 / 2);
    char* wreg = w + HSZ * 13 / 2;
    unsigned short* wvalT  = (unsigned short*)wreg;
    unsigned short* woaT   = wvalT + 256 * 256;       // [384][256]
    unsigned short* woutT  = woaT + 384 * 256;
    unsigned short* w1T    = woutT + 256 * 256;
    unsigned short* w2T    = w1T + 1024 * 256;
    float*          bcat   = (float*)(w2T + 256 * 1024);

    const dim3 blk(256);

    // 1. prepass: sb = bf16(src), qs = bf16(src+pos)
    prepass<<<dim3(NTOK / 4), blk, 0, stream>>>(src, pos, sb, qs);

    // 2. all weight transposes + bias concat (one dispatch)
    transpose_all<<<dim3(737), dim3(32, 8), 0, stream>>>(
        w_val, w_off, w_att, w_out, w1, w2, b_off, b_att,
        wvalT, woaT, woutT, w1T, w2T, bcat);

    // 3. value = sb @ w_val + b_val (masked) -> vT head-major
    gemm_mfma<<<dim3(1, NTOK / TM), blk, 0, stream>>>(
        sb, wvalT, b_val, vT, NTOK, 256, 256, 0, 1, mask);

    // 4. qproj = qs @ [w_off|w_att] + bcat -> qpb [NTOK][384]
    gemm_mfma<<<dim3(2, NTOK / TM), blk, 0, stream>>>(
        qs, woaT, bcat, qpb, NTOK, 384, 256, 0, 0, nullptr);

    // 5. softmax + bilinear sampling -> samp16 (qs dead)
    sample_kernel<<<dim3(16 * (LTOK / 16)), blk, 0, stream>>>(
        vT, qpb, ref, sshap, lstrt, samp16);

    // 6. attn_out = samp @ w_out + b_out -> aof16
    gemm_mfma<<<dim3(1, NTOK / TM), blk, 0, stream>>>(
        samp16, woutT, b_out, aof16, NTOK, 256, 256, 0, 0, nullptr);

    // 7. x = LN1(sb + aof16) -> xb bf16
    ln_kernel<<<dim3(NTOK / 4), blk, 0, stream>>>(
        sb, aof16, ln1g, ln1b, nullptr, xb);

    // 8. hidden = relu(xb @ w1 + b1) -> hidb (overlays dead regions)
    gemm_mfma<<<dim3(4, NTOK / TM), blk, 0, stream>>>(
        xb, w1T, b1, hidb, NTOK, DFFN, 256, 1, 0, nullptr);

    // 9. ffn = hidb @ w2 + b2 -> ffb (sb region, dead)
    gemm_mfma<<<dim3(1, NTOK / TM), blk, 0, stream>>>(
        hidb, w2T, b2, ffb, NTOK, 256, DFFN, 0, 0, nullptr);

    // 10. out = LN2(xb + ffb)
    ln_kernel<<<dim3(NTOK / 4), blk, 0, stream>>>(
        xb, ffb, ln2g, ln2b, out, nullptr);
}

// Round 9
// 481.729 us; speedup vs baseline: 1.1671x; 1.0009x over previous
//
#include <hip/hip_runtime.h>
#include <hip/hip_bf16.h>

// Problem constants
#define BSZ      2
#define LTOK     21760            // 128*128 + 64*64 + 32*32 + 16*16
#define NTOK     (BSZ * LTOK)     // 43520 = 128 * 340
#define DMODEL   256
#define DFFN     1024

typedef __attribute__((ext_vector_type(8))) short short8;   // 8 bf16 = 4 VGPRs
typedef __attribute__((ext_vector_type(4))) float f32x4;

__device__ __forceinline__ unsigned short f2bf(float x) {
    __hip_bfloat16 h = __float2bfloat16(x);
    return *reinterpret_cast<unsigned short*>(&h);
}
__device__ __forceinline__ float bf2f(unsigned short u) {
    union { unsigned int i; float f; } c; c.i = ((unsigned int)u) << 16; return c.f;
}
__device__ __forceinline__ float bflo(unsigned int u) {
    union { unsigned int i; float f; } c; c.i = u << 16; return c.f;
}
__device__ __forceinline__ float bfhi(unsigned int u) {
    union { unsigned int i; float f; } c; c.i = u & 0xffff0000u; return c.f;
}

#define TM 128
#define TN 256
#define TBK 32
#define EBS 264   // epilogue LDS row stride in ushorts (528 B, 16B-aligned)

// ---------------------------------------------------------------------------
// Shared GEMM core: 128x256 tile, BK=32, 4 waves 2x2, wave = 4x8 MFMA 16x16x32.
// Computes acc for tile (bm, bn) of C = A @ Bt^T.  N-guard via row clamp.
// ---------------------------------------------------------------------------
__device__ __forceinline__ void gemm_core(
    const unsigned short* __restrict__ A,
    const unsigned short* __restrict__ Bt,
    unsigned short* sA, unsigned short* sB,
    int bm, int bn, int N, int K,
    int tid, int lane, int wm, int wn,
    f32x4 acc[4][8])
{
    const int sr = tid >> 6;
    const int fr = lane & 15;
    const int fk = (lane >> 4) * 8;

    for (int k0 = 0; k0 < K; k0 += TBK) {
        #pragma unroll
        for (int rr = 0; rr < 2; ++rr) {
            const int s = sr + rr * 4;
            const size_t grow = (size_t)(bm + s * 16 + fr);
            *(uint4*)&sA[s * 512 + lane * 8] = *(const uint4*)(A + grow * K + k0 + fk);
        }
        #pragma unroll
        for (int rr = 0; rr < 4; ++rr) {
            const int s = sr + rr * 4;
            int gn = bn + s * 16 + fr;
            gn = min(gn, N - 1);
            *(uint4*)&sB[s * 512 + lane * 8] = *(const uint4*)(Bt + (size_t)gn * K + k0 + fk);
        }
        __syncthreads();

        short8 af[4], bfr[8];
        #pragma unroll
        for (int i = 0; i < 4; ++i)
            af[i] = *(const short8*)&sA[(wm * 4 + i) * 512 + lane * 8];
        #pragma unroll
        for (int j = 0; j < 8; ++j)
            bfr[j] = *(const short8*)&sB[(wn * 8 + j) * 512 + lane * 8];
        #pragma unroll
        for (int i = 0; i < 4; ++i)
            #pragma unroll
            for (int j = 0; j < 8; ++j)
                acc[i][j] = __builtin_amdgcn_mfma_f32_16x16x32_bf16(
                    af[i], bfr[j], acc[i][j], 0, 0, 0);
        __syncthreads();
    }
}

// ---------------------------------------------------------------------------
// Plain GEMM (ffn1): C row-major bf16, optional relu.
// ---------------------------------------------------------------------------
__global__ __launch_bounds__(256, 2) void gemm_mfma(
    const unsigned short* __restrict__ A,
    const unsigned short* __restrict__ Bt, const float* __restrict__ bias,
    unsigned short* __restrict__ Cb,
    int M, int N, int K, int relu)
{
    __shared__ __align__(16) unsigned short smem[TM * TBK + TN * TBK];
    const int tid  = threadIdx.x;
    const int lane = tid & 63;
    const int wave = tid >> 6;
    const int wm = wave >> 1, wn = wave & 1;
    const int bm = blockIdx.y * TM;
    const int bn = blockIdx.x * TN;

    f32x4 acc[4][8];
    #pragma unroll
    for (int i = 0; i < 4; ++i)
        #pragma unroll
        for (int j = 0; j < 8; ++j)
            acc[i][j] = (f32x4){0.f, 0.f, 0.f, 0.f};

    gemm_core(A, Bt, smem, smem + TM * TBK, bm, bn, N, K, tid, lane, wm, wn, acc);

    const int r0 = (lane >> 4) * 4;
    const int c0 = lane & 15;
    unsigned short* eb = smem;
    #pragma unroll
    for (int i = 0; i < 4; ++i) {
        if (i) __syncthreads();
        #pragma unroll
        for (int j = 0; j < 8; ++j) {
            const int col = bn + wn * 128 + j * 16 + c0;
            const float bj = (col < N) ? bias[col] : 0.f;
            #pragma unroll
            for (int r = 0; r < 4; ++r) {
                float v = acc[i][j][r] + bj;
                if (relu) v = fmaxf(v, 0.f);
                eb[(wm * 16 + r0 + r) * EBS + wn * 128 + j * 16 + c0] = f2bf(v);
            }
        }
        __syncthreads();
        #pragma unroll
        for (int qq = 0; qq < 4; ++qq) {
            const int q  = tid + qq * 256;
            const int rl = q >> 5;
            const int ch = q & 31;
            const int grow = bm + (rl >> 4) * 64 + i * 16 + (rl & 15);
            const int colb = bn + ch * 8;
            if (colb < N)
                *(uint4*)&Cb[(size_t)grow * N + colb] =
                    *(const uint4*)&eb[rl * EBS + ch * 8];
        }
    }
}

// ---------------------------------------------------------------------------
// Fused projection dispatch: bx=0 -> value (masked, head-major vT out);
// bx=1,2 -> qproj (N=384, row-major out). One launch, 3*(NTOK/TM) blocks.
// ---------------------------------------------------------------------------
__global__ __launch_bounds__(256, 2) void gemm_proj(
    const unsigned short* __restrict__ A0, const unsigned short* __restrict__ B0,
    const float* __restrict__ bias0, unsigned short* __restrict__ C0,
    const unsigned char* __restrict__ mask,
    const unsigned short* __restrict__ A1, const unsigned short* __restrict__ B1,
    const float* __restrict__ bias1, unsigned short* __restrict__ C1)
{
    __shared__ __align__(16) unsigned short smem[TM * TBK + TN * TBK];
    const int tid  = threadIdx.x;
    const int lane = tid & 63;
    const int wave = tid >> 6;
    const int wm = wave >> 1, wn = wave & 1;
    const int bm = blockIdx.y * TM;
    const int bx = blockIdx.x;

    const int isv = (bx == 0);
    const unsigned short* A    = isv ? A0 : A1;
    const unsigned short* Bt   = isv ? B0 : B1;
    const float*          bias = isv ? bias0 : bias1;
    const int N  = isv ? 256 : 384;
    const int bn = isv ? 0 : (bx - 1) * 256;
    const int K  = 256;

    f32x4 acc[4][8];
    #pragma unroll
    for (int i = 0; i < 4; ++i)
        #pragma unroll
        for (int j = 0; j < 8; ++j)
            acc[i][j] = (f32x4){0.f, 0.f, 0.f, 0.f};

    gemm_core(A, Bt, smem, smem + TM * TBK, bm, bn, N, K, tid, lane, wm, wn, acc);

    const int r0 = (lane >> 4) * 4;
    const int c0 = lane & 15;
    unsigned short* eb = smem;
    #pragma unroll
    for (int i = 0; i < 4; ++i) {
        if (i) __syncthreads();
        #pragma unroll
        for (int j = 0; j < 8; ++j) {
            const int col = bn + wn * 128 + j * 16 + c0;
            const float bj = (col < N) ? bias[col] : 0.f;
            #pragma unroll
            for (int r = 0; r < 4; ++r) {
                const int row = bm + wm * 64 + i * 16 + r0 + r;
                float v = acc[i][j][r] + bj;
                if (isv && mask[row]) v = 0.f;
                eb[(wm * 16 + r0 + r) * EBS + wn * 128 + j * 16 + c0] = f2bf(v);
            }
        }
        __syncthreads();
        #pragma unroll
        for (int qq = 0; qq < 4; ++qq) {
            const int q  = tid + qq * 256;
            const int rl = q >> 5;
            const int ch = q & 31;
            const int grow = bm + (rl >> 4) * 64 + i * 16 + (rl & 15);
            const int colb = bn + ch * 8;
            if (colb < N) {
                const uint4 val = *(const uint4*)&eb[rl * EBS + ch * 8];
                if (isv) {
                    const int bb   = grow >= LTOK;
                    const int srow = grow - bb * LTOK;
                    const int hcol = ch >> 2;
                    const int d    = (ch & 3) * 8;
                    *(uint4*)&C0[((size_t)(bb * 8 + hcol) * LTOK + srow) * 32 + d] = val;
                } else {
                    *(uint4*)&C1[(size_t)grow * 384 + colb] = val;
                }
            }
        }
    }
}

// ---------------------------------------------------------------------------
// GEMM + LayerNorm fusion (N=256, grid.x=1 so each block owns full rows):
//   y = LN(resid + A@Bt^T + bias) * g + be
// Per slab (32 rows x 256 cols in LDS): 8 lanes/row, two passes
// (sum/sumsq + shuffle-reduce over 8 lanes, then normalize+store).
// outF (f32) or outB (bf16), exactly one non-null.
// ---------------------------------------------------------------------------
__global__ __launch_bounds__(256, 2) void gemm_ln(
    const unsigned short* __restrict__ A,
    const unsigned short* __restrict__ Bt, const float* __restrict__ bias,
    const unsigned short* __restrict__ resid,
    const float* __restrict__ g, const float* __restrict__ be,
    float* __restrict__ outF, unsigned short* __restrict__ outB, int K)
{
    __shared__ __align__(16) unsigned short smem[TM * TBK + TN * TBK];
    const int tid  = threadIdx.x;
    const int lane = tid & 63;
    const int wave = tid >> 6;
    const int wm = wave >> 1, wn = wave & 1;
    const int bm = blockIdx.y * TM;

    f32x4 acc[4][8];
    #pragma unroll
    for (int i = 0; i < 4; ++i)
        #pragma unroll
        for (int j = 0; j < 8; ++j)
            acc[i][j] = (f32x4){0.f, 0.f, 0.f, 0.f};

    gemm_core(A, Bt, smem, smem + TM * TBK, bm, 0, 256, K, tid, lane, wm, wn, acc);

    const int r0 = (lane >> 4) * 4;
    const int c0 = lane & 15;
    unsigned short* eb = smem;

    #pragma unroll
    for (int i = 0; i < 4; ++i) {
        if (i) __syncthreads();
        // stage slab (gemm result + bias) as bf16
        #pragma unroll
        for (int j = 0; j < 8; ++j) {
            const int col = wn * 128 + j * 16 + c0;
            const float bj = bias[col];
            #pragma unroll
            for (int r = 0; r < 4; ++r)
                eb[(wm * 16 + r0 + r) * EBS + col] = f2bf(acc[i][j][r] + bj);
        }
        __syncthreads();

        // LN over each of the 32 staged rows
        const int row = tid >> 3;            // 0..31
        const int l   = tid & 7;             // lane within row
        const int grow = bm + (row >> 4) * 64 + i * 16 + (row & 15);
        const unsigned short* rr = resid + (size_t)grow * 256 + l * 32;

        float s = 0.f, sq = 0.f;
        #pragma unroll
        for (int k = 0; k < 4; ++k) {
            const uint4 e = *(const uint4*)&eb[row * EBS + l * 32 + k * 8];
            const uint4 rv = *(const uint4*)(rr + k * 8);
            const unsigned int eu[4] = {e.x, e.y, e.z, e.w};
            const unsigned int ru[4] = {rv.x, rv.y, rv.z, rv.w};
            #pragma unroll
            for (int q = 0; q < 4; ++q) {
                const float v0 = bflo(eu[q]) + bflo(ru[q]);
                const float v1 = bfhi(eu[q]) + bfhi(ru[q]);
                s += v0 + v1;
                sq += v0 * v0 + v1 * v1;
            }
        }
        #pragma unroll
        for (int m = 4; m; m >>= 1) {
            s  += __shfl_xor(s, m, 8);
            sq += __shfl_xor(sq, m, 8);
        }
        const float mean = s * (1.f / 256.f);
        const float var  = sq * (1.f / 256.f) - mean * mean;
        const float rs   = rsqrtf(var + 1e-5f);

        #pragma unroll
        for (int k = 0; k < 4; ++k) {
            const int col = l * 32 + k * 8;
            const uint4 e = *(const uint4*)&eb[row * EBS + col];
            const uint4 rv = *(const uint4*)(rr + k * 8);
            const unsigned int eu[4] = {e.x, e.y, e.z, e.w};
            const unsigned int ru[4] = {rv.x, rv.y, rv.z, rv.w};
            float o[8];
            #pragma unroll
            for (int q = 0; q < 4; ++q) {
                const float g0 = g[col + q * 2],     b0 = be[col + q * 2];
                const float g1 = g[col + q * 2 + 1], b1 = be[col + q * 2 + 1];
                o[q * 2]     = (bflo(eu[q]) + bflo(ru[q]) - mean) * rs * g0 + b0;
                o[q * 2 + 1] = (bfhi(eu[q]) + bfhi(ru[q]) - mean) * rs * g1 + b1;
            }
            if (outB) {
                uint4 pk;
                pk.x = (unsigned)f2bf(o[0]) | ((unsigned)f2bf(o[1]) << 16);
                pk.y = (unsigned)f2bf(o[2]) | ((unsigned)f2bf(o[3]) << 16);
                pk.z = (unsigned)f2bf(o[4]) | ((unsigned)f2bf(o[5]) << 16);
                pk.w = (unsigned)f2bf(o[6]) | ((unsigned)f2bf(o[7]) << 16);
                *(uint4*)(outB + (size_t)grow * 256 + col) = pk;
            } else {
                float4 f0 = make_float4(o[0], o[1], o[2], o[3]);
                float4 f1 = make_float4(o[4], o[5], o[6], o[7]);
                *(float4*)(outF + (size_t)grow * 256 + col) = f0;
                *(float4*)(outF + (size_t)grow * 256 + col + 4) = f1;
            }
        }
        __syncthreads();   // eb reads done before next slab staging
    }
}

// ---------------------------------------------------------------------------
// Prepass: sb = bf16(src), qs = bf16(src + pos). Vectorized x4.
// ---------------------------------------------------------------------------
__global__ __launch_bounds__(256) void prepass(
    const float* __restrict__ src, const float* __restrict__ pos,
    unsigned short* __restrict__ sb, unsigned short* __restrict__ qs)
{
    const size_t i = ((size_t)blockIdx.x * 256 + threadIdx.x) * 4;
    const float4 s = *(const float4*)(src + i);
    const float4 p = *(const float4*)(pos + i);
    ushort4 us, uq;
    us.x = f2bf(s.x); us.y = f2bf(s.y); us.z = f2bf(s.z); us.w = f2bf(s.w);
    uq.x = f2bf(s.x + p.x); uq.y = f2bf(s.y + p.y);
    uq.z = f2bf(s.z + p.z); uq.w = f2bf(s.w + p.w);
    *(ushort4*)(sb + i) = us;
    *(ushort4*)(qs + i) = uq;
}

// ---------------------------------------------------------------------------
// All weight transposes (f32 [K][N] -> bf16 [N][K]) + bias concat, 1 dispatch.
// ---------------------------------------------------------------------------
__global__ void transpose_all(
    const float* __restrict__ w_val, const float* __restrict__ w_off,
    const float* __restrict__ w_att, const float* __restrict__ w_out,
    const float* __restrict__ w1,    const float* __restrict__ w2,
    const float* __restrict__ b_off, const float* __restrict__ b_att,
    unsigned short* __restrict__ wvalT, unsigned short* __restrict__ woaT,
    unsigned short* __restrict__ woutT, unsigned short* __restrict__ w1T,
    unsigned short* __restrict__ w2T,   float* __restrict__ bcat)
{
    const int blk = blockIdx.x;
    const int tx = threadIdx.x, ty = threadIdx.y;   // 32 x 8
    if (blk == 736) {
        const int t = ty * 32 + tx;
        bcat[t] = (t < 256) ? b_off[t] : b_att[t - 256];
        if (t + 256 < 384) bcat[t + 256] = b_att[t];
        return;
    }
    const float* W; unsigned short* Wt; int K, N, base;
    if      (blk < 64)  { W = w_val; Wt = wvalT;           K = 256;  N = 256;  base = 0;   }
    else if (blk < 128) { W = w_off; Wt = woaT;            K = 256;  N = 256;  base = 64;  }
    else if (blk < 160) { W = w_att; Wt = woaT + 256*256;  K = 256;  N = 128;  base = 128; }
    else if (blk < 224) { W = w_out; Wt = woutT;           K = 256;  N = 256;  base = 160; }
    else if (blk < 480) { W = w1;    Wt = w1T;             K = 256;  N = 1024; base = 224; }
    else                { W = w2;    Wt = w2T;             K = 1024; N = 256;  base = 480; }
    const int local = blk - base;
    const int kb = local % (K / 32);
    const int nb = local / (K / 32);
    const int k0 = kb * 32, n0 = nb * 32;

    __shared__ float t[32][33];
    #pragma unroll
    for (int i = 0; i < 32; i += 8)
        t[ty + i][tx] = W[(size_t)(k0 + ty + i) * N + n0 + tx];
    __syncthreads();
    #pragma unroll
    for (int i = 0; i < 32; i += 8)
        Wt[(size_t)(n0 + ty + i) * K + k0 + tx] = f2bf(t[tx][ty + i]);
}

// ---------------------------------------------------------------------------
// Fused softmax + bilinear sampling (unchanged from round 8).
// ---------------------------------------------------------------------------
__global__ __launch_bounds__(256) void sample_kernel(
    const unsigned short* __restrict__ vT, const unsigned short* __restrict__ qp,
    const float* __restrict__ ref,
    const int* __restrict__ sshapes, const int* __restrict__ lstart,
    unsigned short* __restrict__ samp)
{
    __shared__ __align__(16) int   s_o[256][4];
    __shared__ __align__(16) float s_w[256][4];

    const int blk   = blockIdx.x;
    const int plane = blk & 15;
    const int chunk = blk >> 4;
    const int b = plane >> 3;
    const int h = plane & 7;
    const int s0 = chunk * 16;
    const int t = threadIdx.x;

    {
        const int tl = t >> 4;
        const int p  = t & 15;
        const int l  = p >> 2;
        const int pp = p & 3;
        const int H = sshapes[2 * l], W = sshapes[2 * l + 1];
        const float Wf = (float)W, Hf = (float)H;
        const size_t tok = (size_t)(b * LTOK + s0 + tl);

        const float ox = bf2f(qp[tok * 384 + h * 32 + l * 8 + pp * 2 + 0]);
        const float oy = bf2f(qp[tok * 384 + h * 32 + l * 8 + pp * 2 + 1]);
        const float rx = ref[tok * 8 + l * 2 + 0];
        const float ry = ref[tok * 8 + l * 2 + 1];

        const float x = (rx + ox / Wf) * Wf - 0.5f;
        const float y = (ry + oy / Hf) * Hf - 0.5f;
        const float x0 = floorf(x), y0 = floorf(y);
        const float dx = x - x0, dy = y - y0;
        const int x0i = (int)x0, y0i = (int)y0;
        const int s = lstart[l];

        const float a = bf2f(qp[tok * 384 + 256 + h * 16 + p]);
        float mx = a;
        #pragma unroll
        for (int m = 8; m; m >>= 1) mx = fmaxf(mx, __shfl_xor(mx, m, 16));
        const float e = __expf(a - mx);
        float ssum = e;
        #pragma unroll
        for (int m = 8; m; m >>= 1) ssum += __shfl_xor(ssum, m, 16);
        const float prob = e / ssum;

        const float cw[4] = {(1.f - dx) * (1.f - dy), dx * (1.f - dy),
                             (1.f - dx) * dy,         dx * dy};
        const int cx[4] = {x0i, x0i + 1, x0i,     x0i + 1};
        const int cy[4] = {y0i, y0i,     y0i + 1, y0i + 1};
        int4   o4;
        float4 w4;
        #pragma unroll
        for (int c = 0; c < 4; ++c) {
            const bool valid = (cx[c] >= 0) & (cx[c] < W) & (cy[c] >= 0) & (cy[c] < H);
            const int xi = min(max(cx[c], 0), W - 1);
            const int yi = min(max(cy[c], 0), H - 1);
            ((int*)&o4)[c]   = (s + yi * W + xi) * 64;
            ((float*)&w4)[c] = valid ? cw[c] * prob : 0.f;
        }
        const int r = p * 16 + tl;
        *(int4*)&s_o[r][0]   = o4;
        *(float4*)&s_w[r][0] = w4;
    }
    __syncthreads();

    const int tl = t >> 4;
    const int dp = t & 15;
    const char* vp = (const char*)(vT + (size_t)plane * LTOK * 32) + dp * 4;
    float acc0 = 0.f, acc1 = 0.f;
    #pragma unroll
    for (int p = 0; p < 16; ++p) {
        const int r = p * 16 + tl;
        const int4   o4 = *(const int4*)&s_o[r][0];
        const float4 w4 = *(const float4*)&s_w[r][0];
        const unsigned int u0 = *(const unsigned int*)(vp + o4.x);
        const unsigned int u1 = *(const unsigned int*)(vp + o4.y);
        const unsigned int u2 = *(const unsigned int*)(vp + o4.z);
        const unsigned int u3 = *(const unsigned int*)(vp + o4.w);
        acc0 = fmaf(w4.x, bflo(u0), acc0); acc1 = fmaf(w4.x, bfhi(u0), acc1);
        acc0 = fmaf(w4.y, bflo(u1), acc0); acc1 = fmaf(w4.y, bfhi(u1), acc1);
        acc0 = fmaf(w4.z, bflo(u2), acc0); acc1 = fmaf(w4.z, bfhi(u2), acc1);
        acc0 = fmaf(w4.w, bflo(u3), acc0); acc1 = fmaf(w4.w, bfhi(u3), acc1);
    }
    const unsigned int o = (unsigned)f2bf(acc0) | ((unsigned)f2bf(acc1) << 16);
    *(unsigned int*)(samp + (size_t)(b * LTOK + s0 + tl) * 256 + h * 32 + dp * 2) = o;
}

// ---------------------------------------------------------------------------
extern "C" void kernel_launch(void* const* d_in, const int* in_sizes, int n_in,
                              void* d_out, int out_size, void* d_ws, size_t ws_size,
                              hipStream_t stream)
{
    const float* src   = (const float*)d_in[0];
    const float* pos   = (const float*)d_in[1];
    const float* ref   = (const float*)d_in[2];
    const int*   sshap = (const int*)d_in[3];
    const int*   lstrt = (const int*)d_in[4];
    const unsigned char* mask = (const unsigned char*)d_in[5];
    const float* w_off = (const float*)d_in[6];
    const float* b_off = (const float*)d_in[7];
    const float* w_att = (const float*)d_in[8];
    const float* b_att = (const float*)d_in[9];
    const float* w_val = (const float*)d_in[10];
    const float* b_val = (const float*)d_in[11];
    const float* w_out = (const float*)d_in[12];
    const float* b_out = (const float*)d_in[13];
    const float* ln1g  = (const float*)d_in[14];
    const float* ln1b  = (const float*)d_in[15];
    const float* w1    = (const float*)d_in[16];
    const float* b1    = (const float*)d_in[17];
    const float* w2    = (const float*)d_in[18];
    const float* b2    = (const float*)d_in[19];
    const float* ln2g  = (const float*)d_in[20];
    const float* ln2b  = (const float*)d_in[21];
    float* out = (float*)d_out;

    // ---- workspace (~146 MB), time-disjoint reuse ----
    const size_t HSZ = (size_t)NTOK * 256 * 2;    // 22.28 MB
    char* w = (char*)d_ws;
    unsigned short* qs     = (unsigned short*)w;
    unsigned short* samp16 = (unsigned short*)w;
    unsigned short* qpb    = (unsigned short*)(w + HSZ);
    unsigned short* vT     = (unsigned short*)(w + HSZ * 5 / 2);
    unsigned short* hidb   = (unsigned short*)w;                 // [NTOK][1024]
    unsigned short* sb     = (unsigned short*)(w + HSZ * 9 / 2);
    unsigned short* xb     = (unsigned short*)(w + HSZ * 11 / 2);
    char* wreg = w + HSZ * 13 / 2;
    unsigned short* wvalT  = (unsigned short*)wreg;
    unsigned short* woaT   = wvalT + 256 * 256;       // [384][256]
    unsigned short* woutT  = woaT + 384 * 256;
    unsigned short* w1T    = woutT + 256 * 256;
    unsigned short* w2T    = w1T + 1024 * 256;
    float*          bcat   = (float*)(w2T + 256 * 1024);

    const dim3 blk(256);

    // 1. prepass: sb = bf16(src), qs = bf16(src+pos)
    prepass<<<dim3(NTOK / 4), blk, 0, stream>>>(src, pos, sb, qs);

    // 2. all weight transposes + bias concat
    transpose_all<<<dim3(737), dim3(32, 8), 0, stream>>>(
        w_val, w_off, w_att, w_out, w1, w2, b_off, b_att,
        wvalT, woaT, woutT, w1T, w2T, bcat);

    // 3. fused: value -> vT (head-major, masked) + qproj -> qpb. 1020 blocks.
    gemm_proj<<<dim3(3, NTOK / TM), blk, 0, stream>>>(
        sb, wvalT, b_val, vT, mask, qs, woaT, bcat, qpb);

    // 4. softmax + bilinear sampling -> samp16 (qs dead)
    sample_kernel<<<dim3(16 * (LTOK / 16)), blk, 0, stream>>>(
        vT, qpb, ref, sshap, lstrt, samp16);

    // 5. xb = LN1(sb + samp @ w_out + b_out)  [fused gemm+LN]
    gemm_ln<<<dim3(1, NTOK / TM), blk, 0, stream>>>(
        samp16, woutT, b_out, sb, ln1g, ln1b, nullptr, xb, 256);

    // 6. hidden = relu(xb @ w1 + b1) -> hidb (overlays dead regions)
    gemm_mfma<<<dim3(4, NTOK / TM), blk, 0, stream>>>(
        xb, w1T, b1, hidb, NTOK, DFFN, 256, 1);

    // 7. out = LN2(xb + hidb @ w2 + b2)  [fused gemm+LN, f32 out]
    gemm_ln<<<dim3(1, NTOK / TM), blk, 0, stream>>>(
        hidb, w2T, b2, xb, ln2g, ln2b, out, nullptr, DFFN);
}